// Round 1
// baseline (239.777 us; speedup 1.0000x reference)
//
#include <hip/hip_runtime.h>
#include <math.h>

#define DIM     512
#define NNODES  10000
#define NEDGES  200000

#define TM 64
#define TN 64
#define TK 32
#define LDSS 68   // LDS row stride (floats): 64 + 4 pad, keeps float4 (16B) alignment

// ---------------------------------------------------------------------------
// Kernel 1: ZW[m][n] = sum_k Z[m][k] * W[k][n]   (fp32, vector ALU)
// 64x64 tile per block, K in chunks of 32, 256 threads, 4x4 acc per thread.
// ---------------------------------------------------------------------------
__global__ __launch_bounds__(256) void gemm_zw(const float* __restrict__ A,
                                               const float* __restrict__ B,
                                               float* __restrict__ C) {
    __shared__ float As[TK][LDSS];  // As[k][m]
    __shared__ float Bs[TK][LDSS];  // Bs[k][n]

    const int t  = threadIdx.x;
    const int m0 = blockIdx.x * TM;
    const int n0 = blockIdx.y * TN;
    const int tx = t & 15;          // micro-tile col group
    const int ty = (t >> 4) & 15;   // micro-tile row group

    // A-staging mapping: 8 lanes cover one row's 32-float K chunk (128B segments)
    const int a_kq  = t & 7;        // which float4 along k
    const int a_row = t >> 3;       // 0..31 (+32 on second pass)
    // B-staging mapping: 16 lanes cover one row's 64-float N chunk (256B segments)
    const int b_n4  = t & 15;
    const int b_k   = t >> 4;       // 0..15 (+16 on second pass)

    float acc[4][4] = {};

    for (int k0 = 0; k0 < DIM; k0 += TK) {
        #pragma unroll
        for (int p = 0; p < 2; ++p) {
            int row = a_row + p * 32;
            int m   = m0 + row;
            float4 v = make_float4(0.f, 0.f, 0.f, 0.f);
            if (m < NNODES)
                v = *(const float4*)(A + (size_t)m * DIM + k0 + a_kq * 4);
            As[a_kq * 4 + 0][row] = v.x;
            As[a_kq * 4 + 1][row] = v.y;
            As[a_kq * 4 + 2][row] = v.z;
            As[a_kq * 4 + 3][row] = v.w;
        }
        #pragma unroll
        for (int p = 0; p < 2; ++p) {
            int k = b_k + p * 16;
            float4 v = *(const float4*)(B + (size_t)(k0 + k) * DIM + n0 + b_n4 * 4);
            *(float4*)&Bs[k][b_n4 * 4] = v;
        }
        __syncthreads();

        #pragma unroll
        for (int kk = 0; kk < TK; ++kk) {
            float4 a4 = *(const float4*)&As[kk][ty * 4];
            float4 b4 = *(const float4*)&Bs[kk][tx * 4];
            float av[4] = {a4.x, a4.y, a4.z, a4.w};
            float bv[4] = {b4.x, b4.y, b4.z, b4.w};
            #pragma unroll
            for (int i = 0; i < 4; ++i)
                #pragma unroll
                for (int j = 0; j < 4; ++j)
                    acc[i][j] = fmaf(av[i], bv[j], acc[i][j]);
        }
        __syncthreads();
    }

    #pragma unroll
    for (int i = 0; i < 4; ++i) {
        int m = m0 + ty * 4 + i;
        if (m < NNODES) {
            float4 v = make_float4(acc[i][0], acc[i][1], acc[i][2], acc[i][3]);
            *(float4*)(C + (size_t)m * DIM + n0 + tx * 4) = v;
        }
    }
}

// ---------------------------------------------------------------------------
// Kernel 2: out[e] = sigmoid( dot(ZW[row_e], Z[col_e]) )
// One 64-lane wave per edge; each lane handles 8 consecutive floats.
// ---------------------------------------------------------------------------
__global__ __launch_bounds__(256) void edge_score(const float* __restrict__ ZW,
                                                  const float* __restrict__ Z,
                                                  const int* __restrict__ eidx,
                                                  float* __restrict__ out) {
    const int e    = blockIdx.x * 4 + (threadIdx.x >> 6);
    const int lane = threadIdx.x & 63;

    const int r = eidx[e];           // batch_edges[0][e]
    const int c = eidx[NEDGES + e];  // batch_edges[1][e]

    const float4* pr = (const float4*)(ZW + (size_t)r * DIM);
    const float4* pc = (const float4*)(Z  + (size_t)c * DIM);

    float4 a0 = pr[lane * 2 + 0];
    float4 a1 = pr[lane * 2 + 1];
    float4 b0 = pc[lane * 2 + 0];
    float4 b1 = pc[lane * 2 + 1];

    float s = a0.x * b0.x;
    s = fmaf(a0.y, b0.y, s);
    s = fmaf(a0.z, b0.z, s);
    s = fmaf(a0.w, b0.w, s);
    s = fmaf(a1.x, b1.x, s);
    s = fmaf(a1.y, b1.y, s);
    s = fmaf(a1.z, b1.z, s);
    s = fmaf(a1.w, b1.w, s);

    #pragma unroll
    for (int off = 32; off > 0; off >>= 1)
        s += __shfl_xor(s, off, 64);

    if (lane == 0)
        out[e] = 1.0f / (1.0f + expf(-s));
}

// ---------------------------------------------------------------------------
extern "C" void kernel_launch(void* const* d_in, const int* in_sizes, int n_in,
                              void* d_out, int out_size, void* d_ws, size_t ws_size,
                              hipStream_t stream) {
    const float* Z  = (const float*)d_in[0];   // [10000][512] fp32
    const float* W  = (const float*)d_in[1];   // [512][512]  fp32
    const int*   EI = (const int*)d_in[2];     // [2][200000] int
    float* out = (float*)d_out;                // [200000] fp32
    float* ZW  = (float*)d_ws;                 // [10000][512] fp32 scratch (19.5 MB)

    dim3 g1((NNODES + TM - 1) / TM, DIM / TN); // (157, 8)
    gemm_zw<<<g1, 256, 0, stream>>>(Z, W, ZW);

    edge_score<<<NEDGES / 4, 256, 0, stream>>>(ZW, Z, EI, out);
}

// Round 2
// 233.687 us; speedup vs baseline: 1.0261x; 1.0261x over previous
//
#include <hip/hip_runtime.h>
#include <math.h>

#define DIM     512
#define NNODES  10000
#define NEDGES  200000

// ---------------------------------------------------------------------------
// GEMM: ZW = Z @ W.  128x64 tile, 256 threads, 8x4 micro-tile, TK=16.
// A staged transposed [k][m] in LDS so micro-tile reads are ds_read_b128.
// ---------------------------------------------------------------------------
#define GTM 128
#define GTN 64
#define GTK 16
#define LDA 132   // As row stride in floats ([k][m]); %4==0 keeps b128 align, 2-way banks
#define LDB 68    // Bs row stride in floats ([k][n])

__global__ __launch_bounds__(256) void gemm_zw(const float* __restrict__ A,
                                               const float* __restrict__ B,
                                               float* __restrict__ C) {
    __shared__ float As[GTK * LDA];
    __shared__ float Bs[GTK * LDB];

    const int t  = threadIdx.x;
    const int m0 = blockIdx.x * GTM;
    const int n0 = blockIdx.y * GTN;
    const int tx = t & 15;   // col group: cols tx*4..tx*4+3
    const int ty = t >> 4;   // row group: rows ty*8..ty*8+7

    float acc[8][4] = {};

    for (int k0 = 0; k0 < DIM; k0 += GTK) {
        // Stage A (128 m x 16 k): 512 float4, 2 per thread, transpose into [k][m].
        #pragma unroll
        for (int p = 0; p < 2; ++p) {
            int f  = t + p * 256;
            int mm = f >> 2;        // 0..127
            int kq = f & 3;         // k quad
            int m  = m0 + mm;
            float4 v = make_float4(0.f, 0.f, 0.f, 0.f);
            if (m < NNODES)
                v = *(const float4*)(A + (size_t)m * DIM + k0 + kq * 4);
            As[(kq * 4 + 0) * LDA + mm] = v.x;
            As[(kq * 4 + 1) * LDA + mm] = v.y;
            As[(kq * 4 + 2) * LDA + mm] = v.z;
            As[(kq * 4 + 3) * LDA + mm] = v.w;
        }
        // Stage B (16 k x 64 n): 256 float4, 1 per thread, native layout.
        {
            int kb = t >> 4, n4 = t & 15;
            *(float4*)&Bs[kb * LDB + n4 * 4] =
                *(const float4*)(B + (size_t)(k0 + kb) * DIM + n0 + n4 * 4);
        }
        __syncthreads();

        #pragma unroll
        for (int kk = 0; kk < GTK; ++kk) {
            float4 a0 = *(const float4*)&As[kk * LDA + ty * 8];
            float4 a1 = *(const float4*)&As[kk * LDA + ty * 8 + 4];
            float4 b  = *(const float4*)&Bs[kk * LDB + tx * 4];
            float av[8] = {a0.x, a0.y, a0.z, a0.w, a1.x, a1.y, a1.z, a1.w};
            float bv[4] = {b.x, b.y, b.z, b.w};
            #pragma unroll
            for (int i = 0; i < 8; ++i)
                #pragma unroll
                for (int j = 0; j < 4; ++j)
                    acc[i][j] = fmaf(av[i], bv[j], acc[i][j]);
        }
        __syncthreads();
    }

    #pragma unroll
    for (int i = 0; i < 8; ++i) {
        int m = m0 + ty * 8 + i;
        if (m < NNODES)
            *(float4*)(C + (size_t)m * DIM + n0 + tx * 4) =
                make_float4(acc[i][0], acc[i][1], acc[i][2], acc[i][3]);
    }
}

// ---------------------------------------------------------------------------
// Counting sort of edges by row index (so ZW[row] is loaded once per row).
// key packs col (14 bits) and original edge id (18 bits): 10000<2^14, 200000<2^18.
// ---------------------------------------------------------------------------
__global__ void zero_counts(int* __restrict__ counts) {
    int i = blockIdx.x * blockDim.x + threadIdx.x;
    if (i < NNODES) counts[i] = 0;
}

__global__ void hist_rows(const int* __restrict__ eidx, int* __restrict__ counts) {
    int e = blockIdx.x * blockDim.x + threadIdx.x;
    if (e < NEDGES) atomicAdd(&counts[eidx[e]], 1);
}

__global__ __launch_bounds__(1024) void scan_counts(const int* __restrict__ counts,
                                                    int* __restrict__ offs,
                                                    int* __restrict__ cursor) {
    __shared__ int part[1024];
    const int t = threadIdx.x;
    int local[10];
    int s = 0;
    if (t < 1000) {
        #pragma unroll
        for (int j = 0; j < 10; ++j) {
            local[j] = counts[t * 10 + j];
            s += local[j];
        }
    }
    part[t] = s;
    __syncthreads();
    for (int off = 1; off < 1024; off <<= 1) {
        int v = (t >= off) ? part[t - off] : 0;
        __syncthreads();
        if (t >= off) part[t] += v;
        __syncthreads();
    }
    if (t < 1000) {
        int run = (t == 0) ? 0 : part[t - 1];
        #pragma unroll
        for (int j = 0; j < 10; ++j) {
            offs[t * 10 + j]   = run;
            cursor[t * 10 + j] = run;
            run += local[j];
        }
    }
    if (t == 0) offs[NNODES] = part[1023];
}

__global__ void scatter_edges(const int* __restrict__ eidx,
                              int* __restrict__ cursor,
                              unsigned* __restrict__ keys) {
    int e = blockIdx.x * blockDim.x + threadIdx.x;
    if (e < NEDGES) {
        int r = eidx[e];
        int c = eidx[NEDGES + e];
        int pos = atomicAdd(&cursor[r], 1);
        keys[pos] = ((unsigned)c << 18) | (unsigned)e;
    }
}

// ---------------------------------------------------------------------------
// Bucketed edge scoring: one block per row; ZW[row] cached in LDS; only Z[col]
// gathered per edge. One wave per edge, shuffle reduce, lane0 sigmoid+scatter.
// ---------------------------------------------------------------------------
__global__ __launch_bounds__(256) void edge_score_b(const float* __restrict__ ZW,
                                                    const float* __restrict__ Z,
                                                    const unsigned* __restrict__ keys,
                                                    const int* __restrict__ offs,
                                                    float* __restrict__ out) {
    __shared__ float row[DIM];
    const int r = blockIdx.x;
    const int start = offs[r];
    const int end   = offs[r + 1];
    if (start == end) return;

    const int t = threadIdx.x;
    if (t < 128)
        *(float4*)&row[t * 4] = *(const float4*)(ZW + (size_t)r * DIM + t * 4);
    __syncthreads();

    const int lane = t & 63;
    const int w    = t >> 6;

    for (int i = start + w; i < end; i += 4) {
        unsigned key = keys[i];
        int c = (int)(key >> 18);
        int e = (int)(key & 0x3FFFFu);

        const float4* pc = (const float4*)(Z + (size_t)c * DIM);
        float4 b0 = pc[lane * 2 + 0];
        float4 b1 = pc[lane * 2 + 1];
        float4 a0 = *(const float4*)&row[lane * 8];
        float4 a1 = *(const float4*)&row[lane * 8 + 4];

        float s = a0.x * b0.x;
        s = fmaf(a0.y, b0.y, s);
        s = fmaf(a0.z, b0.z, s);
        s = fmaf(a0.w, b0.w, s);
        s = fmaf(a1.x, b1.x, s);
        s = fmaf(a1.y, b1.y, s);
        s = fmaf(a1.z, b1.z, s);
        s = fmaf(a1.w, b1.w, s);

        #pragma unroll
        for (int off = 32; off > 0; off >>= 1)
            s += __shfl_xor(s, off, 64);

        if (lane == 0)
            out[e] = 1.0f / (1.0f + expf(-s));
    }
}

// ---------------------------------------------------------------------------
// Fallback (ws too small for sort scratch): one wave per edge, unsorted.
// ---------------------------------------------------------------------------
__global__ __launch_bounds__(256) void edge_score(const float* __restrict__ ZW,
                                                  const float* __restrict__ Z,
                                                  const int* __restrict__ eidx,
                                                  float* __restrict__ out) {
    const int e    = blockIdx.x * 4 + (threadIdx.x >> 6);
    const int lane = threadIdx.x & 63;

    const int r = eidx[e];
    const int c = eidx[NEDGES + e];

    const float4* pr = (const float4*)(ZW + (size_t)r * DIM);
    const float4* pc = (const float4*)(Z  + (size_t)c * DIM);

    float4 a0 = pr[lane * 2 + 0];
    float4 a1 = pr[lane * 2 + 1];
    float4 b0 = pc[lane * 2 + 0];
    float4 b1 = pc[lane * 2 + 1];

    float s = a0.x * b0.x;
    s = fmaf(a0.y, b0.y, s);
    s = fmaf(a0.z, b0.z, s);
    s = fmaf(a0.w, b0.w, s);
    s = fmaf(a1.x, b1.x, s);
    s = fmaf(a1.y, b1.y, s);
    s = fmaf(a1.z, b1.z, s);
    s = fmaf(a1.w, b1.w, s);

    #pragma unroll
    for (int off = 32; off > 0; off >>= 1)
        s += __shfl_xor(s, off, 64);

    if (lane == 0)
        out[e] = 1.0f / (1.0f + expf(-s));
}

// ---------------------------------------------------------------------------
extern "C" void kernel_launch(void* const* d_in, const int* in_sizes, int n_in,
                              void* d_out, int out_size, void* d_ws, size_t ws_size,
                              hipStream_t stream) {
    const float* Z  = (const float*)d_in[0];   // [10000][512] fp32
    const float* W  = (const float*)d_in[1];   // [512][512]  fp32
    const int*   EI = (const int*)d_in[2];     // [2][200000] int32
    float* out = (float*)d_out;                // [200000] fp32

    // Workspace layout
    float* ZW       = (float*)d_ws;                         // 10000*512 floats
    int*   counts   = (int*)(ZW + (size_t)NNODES * DIM);    // NNODES
    int*   offs     = counts + NNODES;                      // NNODES+1
    int*   cursor   = offs + NNODES + 1;                    // NNODES
    unsigned* keys  = (unsigned*)(cursor + NNODES);         // NEDGES
    const size_t need = (size_t)NNODES * DIM * 4 +
                        (size_t)(NNODES * 3 + 1) * 4 + (size_t)NEDGES * 4;

    dim3 g1((NNODES + GTM - 1) / GTM, DIM / GTN);  // (79, 8)
    gemm_zw<<<g1, 256, 0, stream>>>(Z, W, ZW);

    if (ws_size >= need) {
        zero_counts<<<(NNODES + 255) / 256, 256, 0, stream>>>(counts);
        hist_rows<<<(NEDGES + 255) / 256, 256, 0, stream>>>(EI, counts);
        scan_counts<<<1, 1024, 0, stream>>>(counts, offs, cursor);
        scatter_edges<<<(NEDGES + 255) / 256, 256, 0, stream>>>(EI, cursor, keys);
        edge_score_b<<<NNODES, 256, 0, stream>>>(ZW, Z, keys, offs, out);
    } else {
        edge_score<<<NEDGES / 4, 256, 0, stream>>>(ZW, Z, EI, out);
    }
}

// Round 3
// 206.449 us; speedup vs baseline: 1.1614x; 1.1319x over previous
//
#include <hip/hip_runtime.h>
#include <math.h>

#define DIM     512
#define NNODES  10000
#define NEDGES  200000
#define MPAD    10112   // 79 * 128

using short8  = __attribute__((ext_vector_type(8))) short;
using floatx4 = __attribute__((ext_vector_type(4))) float;

__device__ inline unsigned short f32_to_bf16_rn(float x) {
    unsigned u = __float_as_uint(x);
    unsigned r = (u + 0x7FFF + ((u >> 16) & 1)) >> 16;
    return (unsigned short)r;
}
__device__ inline float bf16_to_f32(unsigned short h) {
    return __uint_as_float(((unsigned)h) << 16);
}

// ---------------------------------------------------------------------------
// Split Z (fp32 [10000][512]) -> Zhi, Zlo (bf16 [MPAD][512], pad rows zero).
// 4 elements per thread.
// ---------------------------------------------------------------------------
__global__ __launch_bounds__(256) void split_z(const float* __restrict__ Z,
                                               unsigned short* __restrict__ Zhi,
                                               unsigned short* __restrict__ Zlo) {
    const int base = (blockIdx.x * 256 + threadIdx.x) * 4;
    const int m = base >> 9;
    float4 v = make_float4(0.f, 0.f, 0.f, 0.f);
    if (m < NNODES) v = *(const float4*)(Z + base);
    float x[4] = {v.x, v.y, v.z, v.w};
    ushort4 hi, lo;
    unsigned short* hp = (unsigned short*)&hi;
    unsigned short* lp = (unsigned short*)&lo;
    #pragma unroll
    for (int i = 0; i < 4; ++i) {
        unsigned short h = f32_to_bf16_rn(x[i]);
        hp[i] = h;
        lp[i] = f32_to_bf16_rn(x[i] - bf16_to_f32(h));
    }
    *(ushort4*)(Zhi + base) = hi;
    *(ushort4*)(Zlo + base) = lo;
}

// ---------------------------------------------------------------------------
// Split + transpose W (fp32 [k][n]) -> Wht, Wlt (bf16 [n][k]).
// Thread t: n = t>>7, covers 4 consecutive k. Writes coalesced 8B.
// ---------------------------------------------------------------------------
__global__ __launch_bounds__(256) void split_w(const float* __restrict__ W,
                                               unsigned short* __restrict__ Wht,
                                               unsigned short* __restrict__ Wlt) {
    const int t  = blockIdx.x * 256 + threadIdx.x;   // 65536 threads
    const int n  = t >> 7;
    const int k0 = (t & 127) * 4;
    ushort4 hi, lo;
    unsigned short* hp = (unsigned short*)&hi;
    unsigned short* lp = (unsigned short*)&lo;
    #pragma unroll
    for (int i = 0; i < 4; ++i) {
        float x = W[(size_t)(k0 + i) * DIM + n];
        unsigned short h = f32_to_bf16_rn(x);
        hp[i] = h;
        lp[i] = f32_to_bf16_rn(x - bf16_to_f32(h));
    }
    *(ushort4*)(Wht + (size_t)n * DIM + k0) = hi;
    *(ushort4*)(Wlt + (size_t)n * DIM + k0) = lo;
}

// ---------------------------------------------------------------------------
// MFMA GEMM: ZW[m][n] = sum over 3 segments of Aseg[m][k] * Bseg[n][k]
// (B stored transposed). 128x64 tile, 4 waves, each 64m x 32n = 4x2 MFMA tiles.
// Staging via global_load_lds width 16. K = 3*512.
// ---------------------------------------------------------------------------
__global__ __launch_bounds__(256) void gemm_mfma(const unsigned short* __restrict__ Zhi,
                                                 const unsigned short* __restrict__ Zlo,
                                                 const unsigned short* __restrict__ Wht,
                                                 const unsigned short* __restrict__ Wlt,
                                                 float* __restrict__ C) {
    __shared__ unsigned short ldsA[128 * 32];  // [m][k] rows of 32 bf16 (64B)
    __shared__ unsigned short ldsB[64 * 32];   // [n][k]

    const int t  = threadIdx.x;
    const int m0 = blockIdx.x * 128;
    const int n0 = blockIdx.y * 64;

    const int l  = t & 63;
    const int w  = t >> 6;
    const int wm = (w & 1) * 64;
    const int wn = (w >> 1) * 32;
    const int lm = l & 15;
    const int lq = l >> 4;

    floatx4 acc[4][2] = {};

    // staging indices (constant over K loop)
    const int a_q = t & 3;             // 16B chunk within 64B row
    const int b_n = t >> 2;            // 0..63
    const unsigned wave_slot = (unsigned)(t & 192);  // wave-uniform slot base

    for (int ks = 0; ks < 48; ++ks) {
        const int seg = ks >> 4;
        const int k0  = (ks & 15) * 32;
        const unsigned short* Aseg = (seg == 0) ? Zhi : (seg == 1 ? Zlo : Zhi);
        const unsigned short* Bseg = (seg == 2) ? Wlt : Wht;

        // Stage A: 512 slots of 16B (2 per thread)
        #pragma unroll
        for (int p = 0; p < 2; ++p) {
            const int s = p * 256 + t;
            const int m = s >> 2;
            const unsigned short* src = Aseg + (size_t)(m0 + m) * DIM + k0 + a_q * 8;
            __builtin_amdgcn_global_load_lds(
                (const __attribute__((address_space(1))) void*)src,
                (__attribute__((address_space(3))) void*)&ldsA[(p * 256 + wave_slot) * 8],
                16, 0, 0);
        }
        // Stage B: 256 slots of 16B (1 per thread)
        {
            const unsigned short* src = Bseg + (size_t)(n0 + b_n) * DIM + k0 + a_q * 8;
            __builtin_amdgcn_global_load_lds(
                (const __attribute__((address_space(1))) void*)src,
                (__attribute__((address_space(3))) void*)&ldsB[wave_slot * 8],
                16, 0, 0);
        }
        __syncthreads();

        short8 aF[4], bF[2];
        #pragma unroll
        for (int i = 0; i < 4; ++i)
            aF[i] = *(const short8*)&ldsA[(wm + 16 * i + lm) * 32 + lq * 8];
        #pragma unroll
        for (int j = 0; j < 2; ++j)
            bF[j] = *(const short8*)&ldsB[(wn + 16 * j + lm) * 32 + lq * 8];
        #pragma unroll
        for (int i = 0; i < 4; ++i)
            #pragma unroll
            for (int j = 0; j < 2; ++j)
                acc[i][j] = __builtin_amdgcn_mfma_f32_16x16x32_bf16(
                                aF[i], bF[j], acc[i][j], 0, 0, 0);
        __syncthreads();
    }

    #pragma unroll
    for (int i = 0; i < 4; ++i)
        #pragma unroll
        for (int j = 0; j < 2; ++j)
            #pragma unroll
            for (int r = 0; r < 4; ++r) {
                const int gm = m0 + wm + 16 * i + lq * 4 + r;
                const int gn = n0 + wn + 16 * j + lm;
                if (gm < NNODES)
                    C[(size_t)gm * DIM + gn] = acc[i][j][r];
            }
}

// ---------------------------------------------------------------------------
// fp32 GEMM fallback (ws too small for bf16 split scratch)
// ---------------------------------------------------------------------------
#define GTM 128
#define GTN 64
#define GTK 16
#define LDA 132
#define LDB 68

__global__ __launch_bounds__(256) void gemm_zw(const float* __restrict__ A,
                                               const float* __restrict__ B,
                                               float* __restrict__ C) {
    __shared__ float As[GTK * LDA];
    __shared__ float Bs[GTK * LDB];

    const int t  = threadIdx.x;
    const int m0 = blockIdx.x * GTM;
    const int n0 = blockIdx.y * GTN;
    const int tx = t & 15;
    const int ty = t >> 4;

    float acc[8][4] = {};

    for (int k0 = 0; k0 < DIM; k0 += GTK) {
        #pragma unroll
        for (int p = 0; p < 2; ++p) {
            int f  = t + p * 256;
            int mm = f >> 2;
            int kq = f & 3;
            int m  = m0 + mm;
            float4 v = make_float4(0.f, 0.f, 0.f, 0.f);
            if (m < NNODES)
                v = *(const float4*)(A + (size_t)m * DIM + k0 + kq * 4);
            As[(kq * 4 + 0) * LDA + mm] = v.x;
            As[(kq * 4 + 1) * LDA + mm] = v.y;
            As[(kq * 4 + 2) * LDA + mm] = v.z;
            As[(kq * 4 + 3) * LDA + mm] = v.w;
        }
        {
            int kb = t >> 4, n4 = t & 15;
            *(float4*)&Bs[kb * LDB + n4 * 4] =
                *(const float4*)(B + (size_t)(k0 + kb) * DIM + n0 + n4 * 4);
        }
        __syncthreads();

        #pragma unroll
        for (int kk = 0; kk < GTK; ++kk) {
            float4 a0 = *(const float4*)&As[kk * LDA + ty * 8];
            float4 a1 = *(const float4*)&As[kk * LDA + ty * 8 + 4];
            float4 b  = *(const float4*)&Bs[kk * LDB + tx * 4];
            float av[8] = {a0.x, a0.y, a0.z, a0.w, a1.x, a1.y, a1.z, a1.w};
            float bv[4] = {b.x, b.y, b.z, b.w};
            #pragma unroll
            for (int i = 0; i < 8; ++i)
                #pragma unroll
                for (int j = 0; j < 4; ++j)
                    acc[i][j] = fmaf(av[i], bv[j], acc[i][j]);
        }
        __syncthreads();
    }

    #pragma unroll
    for (int i = 0; i < 8; ++i) {
        int m = m0 + ty * 8 + i;
        if (m < NNODES)
            *(float4*)(C + (size_t)m * DIM + n0 + tx * 4) =
                make_float4(acc[i][0], acc[i][1], acc[i][2], acc[i][3]);
    }
}

// ---------------------------------------------------------------------------
// Counting sort of edges by row
// ---------------------------------------------------------------------------
__global__ void zero_counts(int* __restrict__ counts) {
    int i = blockIdx.x * blockDim.x + threadIdx.x;
    if (i < NNODES) counts[i] = 0;
}

__global__ void hist_rows(const int* __restrict__ eidx, int* __restrict__ counts) {
    int e = blockIdx.x * blockDim.x + threadIdx.x;
    if (e < NEDGES) atomicAdd(&counts[eidx[e]], 1);
}

__global__ __launch_bounds__(1024) void scan_counts(const int* __restrict__ counts,
                                                    int* __restrict__ offs,
                                                    int* __restrict__ cursor) {
    __shared__ int part[1024];
    const int t = threadIdx.x;
    int local[10];
    int s = 0;
    if (t < 1000) {
        #pragma unroll
        for (int j = 0; j < 10; ++j) {
            local[j] = counts[t * 10 + j];
            s += local[j];
        }
    }
    part[t] = s;
    __syncthreads();
    for (int off = 1; off < 1024; off <<= 1) {
        int v = (t >= off) ? part[t - off] : 0;
        __syncthreads();
        if (t >= off) part[t] += v;
        __syncthreads();
    }
    if (t < 1000) {
        int run = (t == 0) ? 0 : part[t - 1];
        #pragma unroll
        for (int j = 0; j < 10; ++j) {
            offs[t * 10 + j]   = run;
            cursor[t * 10 + j] = run;
            run += local[j];
        }
    }
    if (t == 0) offs[NNODES] = part[1023];
}

__global__ void scatter_edges(const int* __restrict__ eidx,
                              int* __restrict__ cursor,
                              unsigned* __restrict__ keys) {
    int e = blockIdx.x * blockDim.x + threadIdx.x;
    if (e < NEDGES) {
        int r = eidx[e];
        int c = eidx[NEDGES + e];
        int pos = atomicAdd(&cursor[r], 1);
        keys[pos] = ((unsigned)c << 18) | (unsigned)e;
    }
}

// ---------------------------------------------------------------------------
// Bucketed edge scoring (row cached in LDS, row frags hoisted)
// ---------------------------------------------------------------------------
__global__ __launch_bounds__(256) void edge_score_b(const float* __restrict__ ZW,
                                                    const float* __restrict__ Z,
                                                    const unsigned* __restrict__ keys,
                                                    const int* __restrict__ offs,
                                                    float* __restrict__ out) {
    __shared__ float row[DIM];
    const int r = blockIdx.x;
    const int start = offs[r];
    const int end   = offs[r + 1];
    if (start == end) return;

    const int t = threadIdx.x;
    if (t < 128)
        *(float4*)&row[t * 4] = *(const float4*)(ZW + (size_t)r * DIM + t * 4);
    __syncthreads();

    const int lane = t & 63;
    const int w    = t >> 6;

    const float4 a0 = *(const float4*)&row[lane * 8];
    const float4 a1 = *(const float4*)&row[lane * 8 + 4];

    for (int i = start + w; i < end; i += 4) {
        unsigned key = keys[i];
        int c = (int)(key >> 18);
        int e = (int)(key & 0x3FFFFu);

        const float4* pc = (const float4*)(Z + (size_t)c * DIM);
        float4 b0 = pc[lane * 2 + 0];
        float4 b1 = pc[lane * 2 + 1];

        float s = a0.x * b0.x;
        s = fmaf(a0.y, b0.y, s);
        s = fmaf(a0.z, b0.z, s);
        s = fmaf(a0.w, b0.w, s);
        s = fmaf(a1.x, b1.x, s);
        s = fmaf(a1.y, b1.y, s);
        s = fmaf(a1.z, b1.z, s);
        s = fmaf(a1.w, b1.w, s);

        #pragma unroll
        for (int off = 32; off > 0; off >>= 1)
            s += __shfl_xor(s, off, 64);

        if (lane == 0)
            out[e] = 1.0f / (1.0f + expf(-s));
    }
}

// ---------------------------------------------------------------------------
// Fallback edge scoring (unsorted)
// ---------------------------------------------------------------------------
__global__ __launch_bounds__(256) void edge_score(const float* __restrict__ ZW,
                                                  const float* __restrict__ Z,
                                                  const int* __restrict__ eidx,
                                                  float* __restrict__ out) {
    const int e    = blockIdx.x * 4 + (threadIdx.x >> 6);
    const int lane = threadIdx.x & 63;

    const int r = eidx[e];
    const int c = eidx[NEDGES + e];

    const float4* pr = (const float4*)(ZW + (size_t)r * DIM);
    const float4* pc = (const float4*)(Z  + (size_t)c * DIM);

    float4 a0 = pr[lane * 2 + 0];
    float4 a1 = pr[lane * 2 + 1];
    float4 b0 = pc[lane * 2 + 0];
    float4 b1 = pc[lane * 2 + 1];

    float s = a0.x * b0.x;
    s = fmaf(a0.y, b0.y, s);
    s = fmaf(a0.z, b0.z, s);
    s = fmaf(a0.w, b0.w, s);
    s = fmaf(a1.x, b1.x, s);
    s = fmaf(a1.y, b1.y, s);
    s = fmaf(a1.z, b1.z, s);
    s = fmaf(a1.w, b1.w, s);

    #pragma unroll
    for (int off = 32; off > 0; off >>= 1)
        s += __shfl_xor(s, off, 64);

    if (lane == 0)
        out[e] = 1.0f / (1.0f + expf(-s));
}

// ---------------------------------------------------------------------------
extern "C" void kernel_launch(void* const* d_in, const int* in_sizes, int n_in,
                              void* d_out, int out_size, void* d_ws, size_t ws_size,
                              hipStream_t stream) {
    const float* Z  = (const float*)d_in[0];
    const float* W  = (const float*)d_in[1];
    const int*   EI = (const int*)d_in[2];
    float* out = (float*)d_out;

    // Workspace layout (all 16B-aligned chunk sizes)
    char* p = (char*)d_ws;
    float* ZW = (float*)p;               p += (size_t)NNODES * DIM * 4;      // 20.48 MB
    unsigned short* Zhi = (unsigned short*)p; p += (size_t)MPAD * DIM * 2;   // 10.35 MB
    unsigned short* Zlo = (unsigned short*)p; p += (size_t)MPAD * DIM * 2;   // 10.35 MB
    unsigned short* Wht = (unsigned short*)p; p += (size_t)DIM * DIM * 2;    // 0.52 MB
    unsigned short* Wlt = (unsigned short*)p; p += (size_t)DIM * DIM * 2;    // 0.52 MB
    int* counts = (int*)p;               p += (size_t)NNODES * 4;
    int* offs   = (int*)p;               p += (size_t)(NNODES + 1) * 4;
    int* cursor = (int*)p;               p += (size_t)NNODES * 4;
    unsigned* keys = (unsigned*)p;       p += (size_t)NEDGES * 4;
    const size_t need_full = (size_t)(p - (char*)d_ws);
    const size_t need_sort = (size_t)NNODES * DIM * 4 +
                             (size_t)(NNODES * 3 + 1) * 4 + (size_t)NEDGES * 4;

    if (ws_size >= need_full) {
        split_z<<<(MPAD * DIM / 4 + 255) / 256, 256, 0, stream>>>(Z, Zhi, Zlo);
        split_w<<<(DIM * DIM / 4 + 255) / 256, 256, 0, stream>>>(W, Wht, Wlt);
        dim3 g((MPAD / 128), DIM / 64);  // (79, 8)
        gemm_mfma<<<g, 256, 0, stream>>>(Zhi, Zlo, Wht, Wlt, ZW);
    } else {
        dim3 g1((NNODES + GTM - 1) / GTM, DIM / GTN);
        gemm_zw<<<g1, 256, 0, stream>>>(Z, W, ZW);
    }

    if (ws_size >= need_sort) {
        // sort scratch overlaps the bf16 buffers only if full layout didn't fit;
        // recompute pointers for the small layout in that case
        int* counts2 = counts; int* offs2 = offs; int* cursor2 = cursor; unsigned* keys2 = keys;
        if (ws_size < need_full) {
            char* q = (char*)d_ws + (size_t)NNODES * DIM * 4;
            counts2 = (int*)q;  q += (size_t)NNODES * 4;
            offs2   = (int*)q;  q += (size_t)(NNODES + 1) * 4;
            cursor2 = (int*)q;  q += (size_t)NNODES * 4;
            keys2   = (unsigned*)q;
        }
        zero_counts<<<(NNODES + 255) / 256, 256, 0, stream>>>(counts2);
        hist_rows<<<(NEDGES + 255) / 256, 256, 0, stream>>>(EI, counts2);
        scan_counts<<<1, 1024, 0, stream>>>(counts2, offs2, cursor2);
        scatter_edges<<<(NEDGES + 255) / 256, 256, 0, stream>>>(EI, cursor2, keys2);
        edge_score_b<<<NNODES, 256, 0, stream>>>(ZW, Z, keys2, offs2, out);
    } else {
        edge_score<<<NEDGES / 4, 256, 0, stream>>>(ZW, Z, EI, out);
    }
}

// Round 4
// 199.203 us; speedup vs baseline: 1.2037x; 1.0364x over previous
//
#include <hip/hip_runtime.h>
#include <math.h>

#define DIM     512
#define NNODES  10000
#define NEDGES  200000
#define MPAD    10112   // 79 * 128

using short8  = __attribute__((ext_vector_type(8))) short;
using floatx4 = __attribute__((ext_vector_type(4))) float;

__device__ inline unsigned short f32_to_bf16_rn(float x) {
    unsigned u = __float_as_uint(x);
    unsigned r = (u + 0x7FFF + ((u >> 16) & 1)) >> 16;
    return (unsigned short)r;
}
__device__ inline float bf16_to_f32(unsigned short h) {
    return __uint_as_float(((unsigned)h) << 16);
}

// ---------------------------------------------------------------------------
// Split Z (fp32 [10000][512]) -> Zhi, Zlo (bf16 [MPAD][512], pad rows zero).
// ---------------------------------------------------------------------------
__global__ __launch_bounds__(256) void split_z(const float* __restrict__ Z,
                                               unsigned short* __restrict__ Zhi,
                                               unsigned short* __restrict__ Zlo) {
    const int base = (blockIdx.x * 256 + threadIdx.x) * 4;
    const int m = base >> 9;
    float4 v = make_float4(0.f, 0.f, 0.f, 0.f);
    if (m < NNODES) v = *(const float4*)(Z + base);
    float x[4] = {v.x, v.y, v.z, v.w};
    ushort4 hi, lo;
    unsigned short* hp = (unsigned short*)&hi;
    unsigned short* lp = (unsigned short*)&lo;
    #pragma unroll
    for (int i = 0; i < 4; ++i) {
        unsigned short h = f32_to_bf16_rn(x[i]);
        hp[i] = h;
        lp[i] = f32_to_bf16_rn(x[i] - bf16_to_f32(h));
    }
    *(ushort4*)(Zhi + base) = hi;
    *(ushort4*)(Zlo + base) = lo;
}

// ---------------------------------------------------------------------------
// Split + transpose W (fp32 [k][n]) -> Wht, Wlt (bf16 [n][k]).
// ---------------------------------------------------------------------------
__global__ __launch_bounds__(256) void split_w(const float* __restrict__ W,
                                               unsigned short* __restrict__ Wht,
                                               unsigned short* __restrict__ Wlt) {
    const int t  = blockIdx.x * 256 + threadIdx.x;
    const int n  = t >> 7;
    const int k0 = (t & 127) * 4;
    ushort4 hi, lo;
    unsigned short* hp = (unsigned short*)&hi;
    unsigned short* lp = (unsigned short*)&lo;
    #pragma unroll
    for (int i = 0; i < 4; ++i) {
        float x = W[(size_t)(k0 + i) * DIM + n];
        unsigned short h = f32_to_bf16_rn(x);
        hp[i] = h;
        lp[i] = f32_to_bf16_rn(x - bf16_to_f32(h));
    }
    *(ushort4*)(Wht + (size_t)n * DIM + k0) = hi;
    *(ushort4*)(Wlt + (size_t)n * DIM + k0) = lo;
}

// ---------------------------------------------------------------------------
// MFMA GEMM, m97 structure: 128x128 tile, 4 waves, each 64m x 64n = 4x4 frags
// of 16x16x32. BK=32, K = 3*512 segments (Zhi*Whi + Zlo*Whi + Zhi*Wlo).
// Staging: global_load_lds width 16, 4 slots/thread/K-step.
// ---------------------------------------------------------------------------
__global__ __launch_bounds__(256) void gemm_mfma(const unsigned short* __restrict__ Zhi,
                                                 const unsigned short* __restrict__ Zlo,
                                                 const unsigned short* __restrict__ Wht,
                                                 const unsigned short* __restrict__ Wlt,
                                                 float* __restrict__ C) {
    __shared__ unsigned short ldsA[128 * 32];  // [m][k] rows of 32 bf16 (64B)
    __shared__ unsigned short ldsB[128 * 32];  // [n][k]

    const int t  = threadIdx.x;
    const int m0 = blockIdx.x * 128;
    const int n0 = blockIdx.y * 128;

    const int l  = t & 63;
    const int w  = t >> 6;
    const int wm = (w & 1) * 64;
    const int wn = (w >> 1) * 64;
    const int lm = l & 15;
    const int lq = l >> 4;

    floatx4 acc[4][4] = {};

    const int s_q = t & 3;             // 16B chunk within a 64B row
    const int s_r = t >> 2;            // row 0..63 (+64 for p=1)
    const unsigned wave_slot = (unsigned)(t & 192);

    const unsigned short* __restrict__ Asegs[3] = {Zhi, Zlo, Zhi};
    const unsigned short* __restrict__ Bsegs[3] = {Wht, Wht, Wlt};

    for (int seg = 0; seg < 3; ++seg) {
        const unsigned short* __restrict__ Ap = Asegs[seg] + (size_t)m0 * DIM;
        const unsigned short* __restrict__ Bp = Bsegs[seg] + (size_t)n0 * DIM;

        for (int kc = 0; kc < 16; ++kc) {
            const int k0 = kc * 32;
            // Stage A: 512 slots of 16B (2/thread)
            #pragma unroll
            for (int p = 0; p < 2; ++p) {
                const unsigned short* src = Ap + (size_t)(s_r + p * 64) * DIM + k0 + s_q * 8;
                __builtin_amdgcn_global_load_lds(
                    (const __attribute__((address_space(1))) void*)src,
                    (__attribute__((address_space(3))) void*)&ldsA[(p * 256 + wave_slot) * 8],
                    16, 0, 0);
            }
            // Stage B: 512 slots of 16B (2/thread)
            #pragma unroll
            for (int p = 0; p < 2; ++p) {
                const unsigned short* src = Bp + (size_t)(s_r + p * 64) * DIM + k0 + s_q * 8;
                __builtin_amdgcn_global_load_lds(
                    (const __attribute__((address_space(1))) void*)src,
                    (__attribute__((address_space(3))) void*)&ldsB[(p * 256 + wave_slot) * 8],
                    16, 0, 0);
            }
            __syncthreads();

            short8 aF[4], bF[4];
            #pragma unroll
            for (int i = 0; i < 4; ++i)
                aF[i] = *(const short8*)&ldsA[(wm + 16 * i + lm) * 32 + lq * 8];
            #pragma unroll
            for (int j = 0; j < 4; ++j)
                bF[j] = *(const short8*)&ldsB[(wn + 16 * j + lm) * 32 + lq * 8];
            #pragma unroll
            for (int i = 0; i < 4; ++i)
                #pragma unroll
                for (int j = 0; j < 4; ++j)
                    acc[i][j] = __builtin_amdgcn_mfma_f32_16x16x32_bf16(
                                    aF[i], bF[j], acc[i][j], 0, 0, 0);
            __syncthreads();
        }
    }

    #pragma unroll
    for (int i = 0; i < 4; ++i)
        #pragma unroll
        for (int j = 0; j < 4; ++j)
            #pragma unroll
            for (int r = 0; r < 4; ++r) {
                const int gm = m0 + wm + 16 * i + lq * 4 + r;
                const int gn = n0 + wn + 16 * j + lm;
                if (gm < NNODES)
                    C[(size_t)gm * DIM + gn] = acc[i][j][r];
            }
}

// ---------------------------------------------------------------------------
// fp32 GEMM fallback (ws too small for bf16 split scratch)
// ---------------------------------------------------------------------------
#define GTM 128
#define GTN 64
#define GTK 16
#define LDA 132
#define LDB 68

__global__ __launch_bounds__(256) void gemm_zw(const float* __restrict__ A,
                                               const float* __restrict__ B,
                                               float* __restrict__ C) {
    __shared__ float As[GTK * LDA];
    __shared__ float Bs[GTK * LDB];

    const int t  = threadIdx.x;
    const int m0 = blockIdx.x * GTM;
    const int n0 = blockIdx.y * GTN;
    const int tx = t & 15;
    const int ty = t >> 4;

    float acc[8][4] = {};

    for (int k0 = 0; k0 < DIM; k0 += GTK) {
        #pragma unroll
        for (int p = 0; p < 2; ++p) {
            int f  = t + p * 256;
            int mm = f >> 2;
            int kq = f & 3;
            int m  = m0 + mm;
            float4 v = make_float4(0.f, 0.f, 0.f, 0.f);
            if (m < NNODES)
                v = *(const float4*)(A + (size_t)m * DIM + k0 + kq * 4);
            As[(kq * 4 + 0) * LDA + mm] = v.x;
            As[(kq * 4 + 1) * LDA + mm] = v.y;
            As[(kq * 4 + 2) * LDA + mm] = v.z;
            As[(kq * 4 + 3) * LDA + mm] = v.w;
        }
        {
            int kb = t >> 4, n4 = t & 15;
            *(float4*)&Bs[kb * LDB + n4 * 4] =
                *(const float4*)(B + (size_t)(k0 + kb) * DIM + n0 + n4 * 4);
        }
        __syncthreads();

        #pragma unroll
        for (int kk = 0; kk < GTK; ++kk) {
            float4 a0 = *(const float4*)&As[kk * LDA + ty * 8];
            float4 a1 = *(const float4*)&As[kk * LDA + ty * 8 + 4];
            float4 b  = *(const float4*)&Bs[kk * LDB + tx * 4];
            float av[8] = {a0.x, a0.y, a0.z, a0.w, a1.x, a1.y, a1.z, a1.w};
            float bv[4] = {b.x, b.y, b.z, b.w};
            #pragma unroll
            for (int i = 0; i < 8; ++i)
                #pragma unroll
                for (int j = 0; j < 4; ++j)
                    acc[i][j] = fmaf(av[i], bv[j], acc[i][j]);
        }
        __syncthreads();
    }

    #pragma unroll
    for (int i = 0; i < 8; ++i) {
        int m = m0 + ty * 8 + i;
        if (m < NNODES)
            *(float4*)(C + (size_t)m * DIM + n0 + tx * 4) =
                make_float4(acc[i][0], acc[i][1], acc[i][2], acc[i][3]);
    }
}

// ---------------------------------------------------------------------------
// Counting sort of edges by row
// ---------------------------------------------------------------------------
__global__ void zero_counts(int* __restrict__ counts) {
    int i = blockIdx.x * blockDim.x + threadIdx.x;
    if (i < NNODES) counts[i] = 0;
}

__global__ void hist_rows(const int* __restrict__ eidx, int* __restrict__ counts) {
    int e = blockIdx.x * blockDim.x + threadIdx.x;
    if (e < NEDGES) atomicAdd(&counts[eidx[e]], 1);
}

// Wave-shfl based scan: 1024 threads, 10 counts each; 2 barriers total.
__global__ __launch_bounds__(1024) void scan_counts(const int* __restrict__ counts,
                                                    int* __restrict__ offs,
                                                    int* __restrict__ cursor) {
    __shared__ int wsum[16];
    __shared__ int woff[17];
    const int t    = threadIdx.x;
    const int lane = t & 63;
    const int wv   = t >> 6;

    int local[10];
    int s = 0;
    if (t < 1000) {
        #pragma unroll
        for (int j = 0; j < 10; ++j) {
            local[j] = counts[t * 10 + j];
            s += local[j];
        }
    }
    // inclusive wave scan of s
    int v = s;
    #pragma unroll
    for (int off = 1; off < 64; off <<= 1) {
        int u = __shfl_up(v, off, 64);
        if (lane >= off) v += u;
    }
    if (lane == 63) wsum[wv] = v;
    __syncthreads();
    if (t == 0) {
        int r = 0;
        #pragma unroll
        for (int i = 0; i < 16; ++i) { woff[i] = r; r += wsum[i]; }
        woff[16] = r;
    }
    __syncthreads();
    if (t < 1000) {
        int run = woff[wv] + (v - s);   // exclusive prefix for this thread
        #pragma unroll
        for (int j = 0; j < 10; ++j) {
            offs[t * 10 + j]   = run;
            cursor[t * 10 + j] = run;
            run += local[j];
        }
    }
    if (t == 0) offs[NNODES] = woff[16];
}

__global__ void scatter_edges(const int* __restrict__ eidx,
                              int* __restrict__ cursor,
                              unsigned* __restrict__ keys) {
    int e = blockIdx.x * blockDim.x + threadIdx.x;
    if (e < NEDGES) {
        int r = eidx[e];
        int c = eidx[NEDGES + e];
        int pos = atomicAdd(&cursor[r], 1);
        keys[pos] = ((unsigned)c << 18) | (unsigned)e;
    }
}

// ---------------------------------------------------------------------------
// Bucketed edge scoring; 2-edge unroll per wave iteration for load ILP.
// ---------------------------------------------------------------------------
__device__ inline float edge_dot(const float4 a0, const float4 a1,
                                 const float4 b0, const float4 b1) {
    float s = a0.x * b0.x;
    s = fmaf(a0.y, b0.y, s);
    s = fmaf(a0.z, b0.z, s);
    s = fmaf(a0.w, b0.w, s);
    s = fmaf(a1.x, b1.x, s);
    s = fmaf(a1.y, b1.y, s);
    s = fmaf(a1.z, b1.z, s);
    s = fmaf(a1.w, b1.w, s);
    return s;
}

__global__ __launch_bounds__(256) void edge_score_b(const float* __restrict__ ZW,
                                                    const float* __restrict__ Z,
                                                    const unsigned* __restrict__ keys,
                                                    const int* __restrict__ offs,
                                                    float* __restrict__ out) {
    __shared__ float row[DIM];
    const int r = blockIdx.x;
    const int start = offs[r];
    const int end   = offs[r + 1];
    if (start == end) return;

    const int t = threadIdx.x;
    if (t < 128)
        *(float4*)&row[t * 4] = *(const float4*)(ZW + (size_t)r * DIM + t * 4);
    __syncthreads();

    const int lane = t & 63;
    const int w    = t >> 6;

    const float4 a0 = *(const float4*)&row[lane * 8];
    const float4 a1 = *(const float4*)&row[lane * 8 + 4];

    int i = start + w;
    for (; i + 4 < end; i += 8) {
        unsigned key1 = keys[i];
        unsigned key2 = keys[i + 4];
        int c1 = (int)(key1 >> 18), e1 = (int)(key1 & 0x3FFFFu);
        int c2 = (int)(key2 >> 18), e2 = (int)(key2 & 0x3FFFFu);

        const float4* p1 = (const float4*)(Z + (size_t)c1 * DIM);
        const float4* p2 = (const float4*)(Z + (size_t)c2 * DIM);
        float4 b0 = p1[lane * 2 + 0];
        float4 b1 = p1[lane * 2 + 1];
        float4 b2 = p2[lane * 2 + 0];
        float4 b3 = p2[lane * 2 + 1];

        float s1 = edge_dot(a0, a1, b0, b1);
        float s2 = edge_dot(a0, a1, b2, b3);

        #pragma unroll
        for (int off = 32; off > 0; off >>= 1) {
            s1 += __shfl_xor(s1, off, 64);
            s2 += __shfl_xor(s2, off, 64);
        }
        if (lane == 0) {
            out[e1] = 1.0f / (1.0f + expf(-s1));
            out[e2] = 1.0f / (1.0f + expf(-s2));
        }
    }
    if (i < end) {
        unsigned key = keys[i];
        int c = (int)(key >> 18), e = (int)(key & 0x3FFFFu);
        const float4* pc = (const float4*)(Z + (size_t)c * DIM);
        float4 b0 = pc[lane * 2 + 0];
        float4 b1 = pc[lane * 2 + 1];
        float s = edge_dot(a0, a1, b0, b1);
        #pragma unroll
        for (int off = 32; off > 0; off >>= 1)
            s += __shfl_xor(s, off, 64);
        if (lane == 0)
            out[e] = 1.0f / (1.0f + expf(-s));
    }
}

// ---------------------------------------------------------------------------
// Fallback edge scoring (unsorted)
// ---------------------------------------------------------------------------
__global__ __launch_bounds__(256) void edge_score(const float* __restrict__ ZW,
                                                  const float* __restrict__ Z,
                                                  const int* __restrict__ eidx,
                                                  float* __restrict__ out) {
    const int e    = blockIdx.x * 4 + (threadIdx.x >> 6);
    const int lane = threadIdx.x & 63;

    const int r = eidx[e];
    const int c = eidx[NEDGES + e];

    const float4* pr = (const float4*)(ZW + (size_t)r * DIM);
    const float4* pc = (const float4*)(Z  + (size_t)c * DIM);

    float4 a0 = pr[lane * 2 + 0];
    float4 a1 = pr[lane * 2 + 1];
    float4 b0 = pc[lane * 2 + 0];
    float4 b1 = pc[lane * 2 + 1];

    float s = edge_dot(a0, a1, b0, b1);

    #pragma unroll
    for (int off = 32; off > 0; off >>= 1)
        s += __shfl_xor(s, off, 64);

    if (lane == 0)
        out[e] = 1.0f / (1.0f + expf(-s));
}

// ---------------------------------------------------------------------------
extern "C" void kernel_launch(void* const* d_in, const int* in_sizes, int n_in,
                              void* d_out, int out_size, void* d_ws, size_t ws_size,
                              hipStream_t stream) {
    const float* Z  = (const float*)d_in[0];
    const float* W  = (const float*)d_in[1];
    const int*   EI = (const int*)d_in[2];
    float* out = (float*)d_out;

    char* p = (char*)d_ws;
    float* ZW = (float*)p;               p += (size_t)NNODES * DIM * 4;
    unsigned short* Zhi = (unsigned short*)p; p += (size_t)MPAD * DIM * 2;
    unsigned short* Zlo = (unsigned short*)p; p += (size_t)MPAD * DIM * 2;
    unsigned short* Wht = (unsigned short*)p; p += (size_t)DIM * DIM * 2;
    unsigned short* Wlt = (unsigned short*)p; p += (size_t)DIM * DIM * 2;
    int* counts = (int*)p;               p += (size_t)NNODES * 4;
    int* offs   = (int*)p;               p += (size_t)(NNODES + 1) * 4;
    int* cursor = (int*)p;               p += (size_t)NNODES * 4;
    unsigned* keys = (unsigned*)p;       p += (size_t)NEDGES * 4;
    const size_t need_full = (size_t)(p - (char*)d_ws);
    const size_t need_sort = (size_t)NNODES * DIM * 4 +
                             (size_t)(NNODES * 3 + 1) * 4 + (size_t)NEDGES * 4;

    if (ws_size >= need_full) {
        split_z<<<(MPAD * DIM / 4 + 255) / 256, 256, 0, stream>>>(Z, Zhi, Zlo);
        split_w<<<(DIM * DIM / 4 + 255) / 256, 256, 0, stream>>>(W, Wht, Wlt);
        dim3 g((MPAD / 128), DIM / 128);  // (79, 4)
        gemm_mfma<<<g, 256, 0, stream>>>(Zhi, Zlo, Wht, Wlt, ZW);
    } else {
        dim3 g1((NNODES + GTM - 1) / GTM, DIM / GTN);
        gemm_zw<<<g1, 256, 0, stream>>>(Z, W, ZW);
    }

    if (ws_size >= need_sort) {
        int* counts2 = counts; int* offs2 = offs; int* cursor2 = cursor; unsigned* keys2 = keys;
        if (ws_size < need_full) {
            char* q = (char*)d_ws + (size_t)NNODES * DIM * 4;
            counts2 = (int*)q;  q += (size_t)NNODES * 4;
            offs2   = (int*)q;  q += (size_t)(NNODES + 1) * 4;
            cursor2 = (int*)q;  q += (size_t)NNODES * 4;
            keys2   = (unsigned*)q;
        }
        zero_counts<<<(NNODES + 255) / 256, 256, 0, stream>>>(counts2);
        hist_rows<<<(NEDGES + 255) / 256, 256, 0, stream>>>(EI, counts2);
        scan_counts<<<1, 1024, 0, stream>>>(counts2, offs2, cursor2);
        scatter_edges<<<(NEDGES + 255) / 256, 256, 0, stream>>>(EI, cursor2, keys2);
        edge_score_b<<<NNODES, 256, 0, stream>>>(ZW, Z, keys2, offs2, out);
    } else {
        edge_score<<<NEDGES / 4, 256, 0, stream>>>(ZW, Z, EI, out);
    }
}